// Round 2
// baseline (1518.054 us; speedup 1.0000x reference)
//
#include <hip/hip_runtime.h>

#define NB 64
#define NC 96
#define NHW 56
#define NTOK 49
#define NHEAD 3
#define HD 32
#define SCALE 0.17677669529663687f  // 32^-0.5

// One block per (batch, window). 384 threads = 6 waves.
__global__ __launch_bounds__(384)
void winattn(const float* __restrict__ x,     // [64,96,56,56]
             const float* __restrict__ wqkv,  // [96,288]
             const float* __restrict__ pos,   // [169,3]
             const float* __restrict__ wout,  // [96,96]
             const float* __restrict__ bout,  // [96]
             float* __restrict__ out)         // [64,96,56,56]
{
    __shared__ __align__(16) float xw[NTOK * 100];   // [49][100] pad: float4-aligned rows
    __shared__ __align__(16) float qs[NTOK * HD];    // [49][32] q*scale
    __shared__ __align__(16) float kst[HD * 50];     // [32][50] k transposed (pad 50)
    __shared__ __align__(16) float vs[NTOK * HD];    // [49][32]
    __shared__ __align__(16) float attn[NTOK * NTOK];// [49][49]
    __shared__ __align__(16) float pvt[HD * NTOK];   // [32][49] attn@v transposed

    const int tid = threadIdx.x;
    const int blk = blockIdx.x;
    const int b  = blk >> 6;
    const int w  = blk & 63;
    const int wh = w >> 3, ww = w & 7;
    const int row0 = wh * 7, col0 = ww * 7;

    // ---- load x window -> LDS [t][c]
    const float* xb = x + (size_t)b * NC * NHW * NHW;
    for (int i = tid; i < NTOK * NC; i += 384) {
        int c = i / NTOK, t = i % NTOK;
        int tr = t / 7, tc = t % 7;
        xw[t * 100 + c] = xb[(c * NHW + row0 + tr) * NHW + col0 + tc];
    }

    // persistent projection accumulators (summed over heads)
    float pacc[13];
#pragma unroll
    for (int k = 0; k < 13; ++k) pacc[k] = 0.f;

    const int col = tid % 96;   // output channel / qkv column owner
    const int tg  = tid / 96;   // 0..3 token group

    __syncthreads();

    for (int h = 0; h < NHEAD; ++h) {
        // ---- qkv for this head: thread owns one of 96 columns, 12-13 tokens
        {
            const int which = col >> 5;       // 0=q 1=k 2=v
            const int d = col & 31;
            const int wcol = which * 96 + h * HD + d;
            float acc[13];
#pragma unroll
            for (int k = 0; k < 13; ++k) acc[k] = 0.f;
            for (int c4 = 0; c4 < 24; ++c4) {
                const float w0 = wqkv[(c4 * 4 + 0) * 288 + wcol];
                const float w1 = wqkv[(c4 * 4 + 1) * 288 + wcol];
                const float w2 = wqkv[(c4 * 4 + 2) * 288 + wcol];
                const float w3 = wqkv[(c4 * 4 + 3) * 288 + wcol];
#pragma unroll
                for (int k = 0; k < 13; ++k) {
                    int t = tg + k * 4;
                    if (t < NTOK) {
                        const float4 xv = *(const float4*)&xw[t * 100 + c4 * 4];
                        acc[k] = fmaf(xv.x, w0, fmaf(xv.y, w1,
                                 fmaf(xv.z, w2, fmaf(xv.w, w3, acc[k]))));
                    }
                }
            }
#pragma unroll
            for (int k = 0; k < 13; ++k) {
                int t = tg + k * 4;
                if (t < NTOK) {
                    if (which == 0)      qs[t * HD + d] = acc[k] * SCALE;
                    else if (which == 1) kst[d * 50 + t] = acc[k];
                    else                 vs[t * HD + d] = acc[k];
                }
            }
        }
        __syncthreads();

        // ---- dots + relative position bias
        for (int p = tid; p < NTOK * NTOK; p += 384) {
            int i = p / NTOK, j = p % NTOK;
            float s = 0.f;
#pragma unroll 8
            for (int d = 0; d < HD; ++d)
                s = fmaf(qs[i * HD + d], kst[d * 50 + j], s);
            int xi = i / 7, yi = i % 7, xj = j / 7, yj = j % 7;
            int ridx = (xj - xi + 6) * 13 + (yj - yi + 6);
            attn[p] = s + pos[ridx * NHEAD + h];
        }
        __syncthreads();

        // ---- softmax per row (thread-per-row; small)
        if (tid < NTOK) {
            const int i = tid;
            float m = -1e30f;
            for (int j = 0; j < NTOK; ++j) m = fmaxf(m, attn[i * NTOK + j]);
            float ssum = 0.f;
            for (int j = 0; j < NTOK; ++j) {
                float e = expf(attn[i * NTOK + j] - m);
                attn[i * NTOK + j] = e;
                ssum += e;
            }
            float inv = 1.f / ssum;
            for (int j = 0; j < NTOK; ++j) attn[i * NTOK + j] *= inv;
        }
        __syncthreads();

        // ---- PV: pvt[d][t] = sum_j attn[t][j] * v[j][d]
        for (int p = tid; p < NTOK * HD; p += 384) {
            int d = p & 31, t = p >> 5;
            float s = 0.f;
            for (int j = 0; j < NTOK; ++j)
                s = fmaf(attn[t * NTOK + j], vs[j * HD + d], s);
            pvt[d * NTOK + t] = s;
        }
        __syncthreads();

        // ---- partial projection: pacc += pvt[d][t] * wout[(h*32+d)][o]
        {
            const int o = col;
#pragma unroll 4
            for (int d = 0; d < HD; ++d) {
                const float wv = wout[(h * HD + d) * 96 + o];
#pragma unroll
                for (int k = 0; k < 13; ++k) {
                    int t = tg + k * 4;
                    if (t < NTOK)
                        pacc[k] = fmaf(pvt[d * NTOK + t], wv, pacc[k]);
                }
            }
        }
        __syncthreads();
    }

    // ---- stage to LDS (reuse xw) and store coalesced in [b,c,H,W]
    {
#pragma unroll
        for (int k = 0; k < 13; ++k) {
            int t = tg + k * 4;
            if (t < NTOK) xw[t * 97 + col] = pacc[k];
        }
    }
    __syncthreads();
    for (int i = tid; i < NTOK * NC; i += 384) {
        int o = i / NTOK, t = i % NTOK;
        int tr = t / 7, tc = t % 7;
        out[((size_t)b * NC + o) * NHW * NHW + (row0 + tr) * NHW + col0 + tc]
            = xw[t * 97 + o] + bout[o];
    }
}

extern "C" void kernel_launch(void* const* d_in, const int* in_sizes, int n_in,
                              void* d_out, int out_size, void* d_ws, size_t ws_size,
                              hipStream_t stream) {
    const float* x    = (const float*)d_in[0];
    const float* wqkv = (const float*)d_in[1];
    const float* pos  = (const float*)d_in[2];
    const float* wout = (const float*)d_in[3];
    const float* bout = (const float*)d_in[4];
    float* outp = (float*)d_out;
    winattn<<<dim3(NB * 64), dim3(384), 0, stream>>>(x, wqkv, pos, wout, bout, outp);
}

// Round 3
// 173.764 us; speedup vs baseline: 8.7363x; 8.7363x over previous
//
#include <hip/hip_runtime.h>

typedef __bf16 bf16x8 __attribute__((ext_vector_type(8)));
typedef float  f32x4  __attribute__((ext_vector_type(4)));

#define SCALE 0.17677669529663687f  // 32^-0.5

__device__ __forceinline__ unsigned short f2bf(float f) {
    unsigned int u = __float_as_uint(f);
    u += 0x7fffu + ((u >> 16) & 1u);
    return (unsigned short)(u >> 16);
}
__device__ __forceinline__ float bf2f(unsigned short s) {
    return __uint_as_float(((unsigned int)s) << 16);
}

// ws layout (bytes)
#define WQKVT_OFF 0          // ushort [288][96]  (q cols pre-scaled)
#define WOUTT_OFF 55296      // ushort [96][96]   (transposed)
#define BIAS_OFF  73728      // float  [3][64][64] (pad j>=49 -> -1e30)

__global__ __launch_bounds__(256)
void prep(const float* __restrict__ wqkv, const float* __restrict__ pos,
          const float* __restrict__ wout, unsigned short* __restrict__ wqkvT,
          unsigned short* __restrict__ woutT, float* __restrict__ biasw)
{
    int tid = blockIdx.x * 256 + threadIdx.x;
    int stride = gridDim.x * 256;
    for (int i = tid; i < 288 * 96; i += stride) {
        int n = i / 96, c = i % 96;
        float v = wqkv[c * 288 + n];
        if (n < 96) v *= SCALE;
        wqkvT[i] = f2bf(v);
    }
    for (int i = tid; i < 96 * 96; i += stride) {
        int o = i / 96, c = i % 96;
        woutT[i] = f2bf(wout[c * 96 + o]);
    }
    for (int i = tid; i < 3 * 64 * 64; i += stride) {
        int h = i >> 12, r = i & 4095, ii = r >> 6, j = r & 63;
        float v;
        if (j >= 49) v = -1e30f;          // mask pad keys
        else if (ii >= 49) v = 0.f;       // pad query rows: anything finite
        else {
            int ridx = ((j / 7) - (ii / 7) + 6) * 13 + ((j % 7) - (ii % 7) + 6);
            v = pos[ridx * 3 + h];
        }
        biasw[i] = v;
    }
}

// One block per (batch, window). 512 threads = 8 waves. Tokens padded 49->64.
__global__ __launch_bounds__(512)
void winattn(const float* __restrict__ x, const float* __restrict__ bout,
             const unsigned short* __restrict__ wqkvT,
             const unsigned short* __restrict__ woutT,
             const float* __restrict__ biasw, float* __restrict__ out)
{
    __shared__ __align__(16) unsigned char smem[62976];
    unsigned short* xw   = (unsigned short*)smem;            // [64][104] bf16 (row pad: 2-way banks)
    unsigned short* oall = (unsigned short*)smem;            // [64][104] (overlay: xw dead after qkv)
    unsigned short* qall = (unsigned short*)(smem + 13312);  // [64][104]
    unsigned short* kall = (unsigned short*)(smem + 26624);  // [64][104]
    unsigned short* vt   = (unsigned short*)(smem + 39936);  // [96][72] v transposed
    float*          fin  = (float*)(smem + 13312);           // [96][68] (overlay q/k: dead by proj)
    unsigned short* sP   = (unsigned short*)(smem + 53760);  // [64][72] scores/probs

    const int tid = threadIdx.x;
    const int lane = tid & 63;
    const int w  = tid >> 6;      // wave 0..7
    const int lr = lane & 15;     // row-of-A / col-of-B / col-of-C
    const int lk = lane >> 4;     // k-group (A/B), row-group (C)

    const int blk = blockIdx.x;
    const int b = blk >> 6, win = blk & 63;
    const int row0 = (win >> 3) * 7, col0 = (win & 7) * 7;

    // ---- stage x window -> bf16 LDS [64][104], zero pad rows
    const float* xb = x + (size_t)b * 96 * 3136;
    for (int i = tid; i < 96 * 64; i += 512) {
        int c = i >> 6, t = i & 63;
        float v = 0.f;
        if (t < 49) v = xb[(c * 56 + row0 + t / 7) * 56 + col0 + (t % 7)];
        xw[t * 104 + c] = f2bf(v);
    }
    __syncthreads();

    // ---- QKV: [64x96] @ [96x288]; 72 tiles of 16x16, 9 per wave
    {
        const int mi = w & 3;          // fixed row-tile per wave
        const int nb = w >> 2;         // 0/1 -> even/odd ni
        f32x4 acc[9];
#pragma unroll
        for (int i = 0; i < 9; ++i) acc[i] = (f32x4){0.f, 0.f, 0.f, 0.f};
#pragma unroll
        for (int k = 0; k < 3; ++k) {
            bf16x8 a = *(const bf16x8*)&xw[(mi * 16 + lr) * 104 + k * 32 + lk * 8];
#pragma unroll
            for (int idx = 0; idx < 9; ++idx) {
                int ni = 2 * idx + nb;
                bf16x8 bb = *(const bf16x8*)&wqkvT[(ni * 16 + lr) * 96 + k * 32 + lk * 8];
                acc[idx] = __builtin_amdgcn_mfma_f32_16x16x32_bf16(a, bb, acc[idx], 0, 0, 0);
            }
        }
#pragma unroll
        for (int idx = 0; idx < 9; ++idx) {
            int n0 = (2 * idx + nb) * 16;
            if (n0 < 96) {            // q
#pragma unroll
                for (int e = 0; e < 4; ++e)
                    qall[(mi * 16 + lk * 4 + e) * 104 + n0 + lr] = f2bf(acc[idx][e]);
            } else if (n0 < 192) {    // k
#pragma unroll
                for (int e = 0; e < 4; ++e)
                    kall[(mi * 16 + lk * 4 + e) * 104 + n0 - 96 + lr] = f2bf(acc[idx][e]);
            } else {                  // v -> transposed [d][tok]
                int d = n0 - 192 + lr;
                ushort4 pk;
                pk.x = f2bf(acc[idx][0]); pk.y = f2bf(acc[idx][1]);
                pk.z = f2bf(acc[idx][2]); pk.w = f2bf(acc[idx][3]);
                *(ushort4*)&vt[d * 72 + mi * 16 + lk * 4] = pk;
            }
        }
    }

    // ---- per-head attention
    for (int h = 0; h < 3; ++h) {
        __syncthreads();   // q/k/v ready (h=0) or sP free after prev PV

        // S = Qs @ K^T + bias: 16 tiles, 2 per wave
        {
            const int ni = w & 3;
#pragma unroll
            for (int idx = 0; idx < 2; ++idx) {
                int mi = (w >> 2) + 2 * idx;
                bf16x8 a  = *(const bf16x8*)&qall[(mi * 16 + lr) * 104 + h * 32 + lk * 8];
                bf16x8 bb = *(const bf16x8*)&kall[(ni * 16 + lr) * 104 + h * 32 + lk * 8];
                f32x4 acc = (f32x4){0.f, 0.f, 0.f, 0.f};
                acc = __builtin_amdgcn_mfma_f32_16x16x32_bf16(a, bb, acc, 0, 0, 0);
#pragma unroll
                for (int e = 0; e < 4; ++e) {
                    int i = mi * 16 + lk * 4 + e, j = ni * 16 + lr;
                    float sv = acc[e] + biasw[(h << 12) + (i << 6) + j];
                    sP[i * 72 + j] = f2bf(sv);
                }
            }
        }
        __syncthreads();

        // softmax: 8 threads per row, 8 cols each
        {
            const int i = tid >> 3, sub = tid & 7;
            const unsigned short* sr = &sP[i * 72 + sub * 8];
            float v[8];
#pragma unroll
            for (int e = 0; e < 8; ++e) v[e] = bf2f(sr[e]);
            float m = v[0];
#pragma unroll
            for (int e = 1; e < 8; ++e) m = fmaxf(m, v[e]);
            m = fmaxf(m, __shfl_xor(m, 1));
            m = fmaxf(m, __shfl_xor(m, 2));
            m = fmaxf(m, __shfl_xor(m, 4));
            float s = 0.f;
#pragma unroll
            for (int e = 0; e < 8; ++e) { v[e] = __expf(v[e] - m); s += v[e]; }
            s += __shfl_xor(s, 1);
            s += __shfl_xor(s, 2);
            s += __shfl_xor(s, 4);
            float inv = 1.f / s;
            unsigned short* swr = &sP[i * 72 + sub * 8];
#pragma unroll
            for (int e = 0; e < 8; ++e) swr[e] = f2bf(v[e] * inv);
        }
        __syncthreads();

        // PV: O_h[64x32] = P[64x64] @ V_h[64x32]; 8 tiles, 1 per wave
        {
            const int mi = w >> 1, ni = w & 1;
            f32x4 acc = (f32x4){0.f, 0.f, 0.f, 0.f};
#pragma unroll
            for (int kk = 0; kk < 2; ++kk) {
                bf16x8 a  = *(const bf16x8*)&sP[(mi * 16 + lr) * 72 + kk * 32 + lk * 8];
                bf16x8 bb = *(const bf16x8*)&vt[(h * 32 + ni * 16 + lr) * 72 + kk * 32 + lk * 8];
                acc = __builtin_amdgcn_mfma_f32_16x16x32_bf16(a, bb, acc, 0, 0, 0);
            }
#pragma unroll
            for (int e = 0; e < 4; ++e)
                oall[(mi * 16 + lk * 4 + e) * 104 + h * 32 + ni * 16 + lr] = f2bf(acc[e]);
        }
    }
    __syncthreads();

    // ---- proj: [64x96] @ [96x96] + bias; 24 tiles, 3 per wave
    {
        const int mi = w & 3;
        const int nb = w >> 2;
        f32x4 acc[3];
#pragma unroll
        for (int i = 0; i < 3; ++i) acc[i] = (f32x4){0.f, 0.f, 0.f, 0.f};
#pragma unroll
        for (int k = 0; k < 3; ++k) {
            bf16x8 a = *(const bf16x8*)&oall[(mi * 16 + lr) * 104 + k * 32 + lk * 8];
#pragma unroll
            for (int idx = 0; idx < 3; ++idx) {
                int ni = 2 * idx + nb;
                bf16x8 bb = *(const bf16x8*)&woutT[(ni * 16 + lr) * 96 + k * 32 + lk * 8];
                acc[idx] = __builtin_amdgcn_mfma_f32_16x16x32_bf16(a, bb, acc[idx], 0, 0, 0);
            }
        }
#pragma unroll
        for (int idx = 0; idx < 3; ++idx) {
            int n0 = (2 * idx + nb) * 16;
            float bias = bout[n0 + lr];
            float4 f;
            f.x = acc[idx][0] + bias; f.y = acc[idx][1] + bias;
            f.z = acc[idx][2] + bias; f.w = acc[idx][3] + bias;
            *(float4*)&fin[(n0 + lr) * 68 + mi * 16 + lk * 4] = f;
        }
    }
    __syncthreads();

    // ---- final store [b, c, H, W]
    for (int i = tid; i < 49 * 96; i += 512) {
        int c = i / 49, t = i % 49;
        out[((size_t)b * 96 + c) * 3136 + (row0 + t / 7) * 56 + col0 + t % 7]
            = fin[c * 68 + t];
    }
}

extern "C" void kernel_launch(void* const* d_in, const int* in_sizes, int n_in,
                              void* d_out, int out_size, void* d_ws, size_t ws_size,
                              hipStream_t stream) {
    const float* x    = (const float*)d_in[0];
    const float* wqkv = (const float*)d_in[1];
    const float* pos  = (const float*)d_in[2];
    const float* wout = (const float*)d_in[3];
    const float* bout = (const float*)d_in[4];
    float* outp = (float*)d_out;

    unsigned short* wqkvT = (unsigned short*)((char*)d_ws + WQKVT_OFF);
    unsigned short* woutT = (unsigned short*)((char*)d_ws + WOUTT_OFF);
    float*          biasw = (float*)((char*)d_ws + BIAS_OFF);

    prep<<<dim3(64), dim3(256), 0, stream>>>(wqkv, pos, wout, wqkvT, woutT, biasw);
    winattn<<<dim3(4096), dim3(512), 0, stream>>>(x, bout, wqkvT, woutT, biasw, outp);
}

// Round 4
// 158.841 us; speedup vs baseline: 9.5571x; 1.0940x over previous
//
#include <hip/hip_runtime.h>

typedef __bf16 bf16x8 __attribute__((ext_vector_type(8)));
typedef float  f32x4  __attribute__((ext_vector_type(4)));

#define SCALE 0.17677669529663687f  // 32^-0.5

__device__ __forceinline__ unsigned short f2bf(float f) {
    unsigned int u = __float_as_uint(f);
    u += 0x7fffu + ((u >> 16) & 1u);
    return (unsigned short)(u >> 16);
}
__device__ __forceinline__ float bf2f(unsigned short s) {
    return __uint_as_float(((unsigned int)s) << 16);
}

// ws layout (bytes)
#define XWIN_OFF  0                  // ushort [64][64][64][96]  padded bf16 windows
#define WQKVT_OFF 50331648           // ushort [288][96] (q cols pre-scaled)
#define WOUTT_OFF 50386944           // ushort [96][96]  (transposed)
#define BIAS_OFF  50405376           // float  [3][64][64] (pad j>=49 -> -1e30)

__global__ __launch_bounds__(256)
void prep(const float* __restrict__ wqkv, const float* __restrict__ pos,
          const float* __restrict__ wout, unsigned short* __restrict__ wqkvT,
          unsigned short* __restrict__ woutT, float* __restrict__ biasw)
{
    int tid = blockIdx.x * 256 + threadIdx.x;
    int stride = gridDim.x * 256;
    for (int i = tid; i < 288 * 96; i += stride) {
        int n = i / 96, c = i % 96;
        float v = wqkv[c * 288 + n];
        if (n < 96) v *= SCALE;
        wqkvT[i] = f2bf(v);
    }
    for (int i = tid; i < 96 * 96; i += stride) {
        int o = i / 96, c = i % 96;
        woutT[i] = f2bf(wout[c * 96 + o]);
    }
    for (int i = tid; i < 3 * 64 * 64; i += stride) {
        int h = i >> 12, r = i & 4095, ii = r >> 6, j = r & 63;
        float v;
        if (j >= 49) v = -1e30f;          // mask pad keys
        else if (ii >= 49) v = 0.f;       // pad query rows: anything finite
        else {
            int ridx = ((j / 7) - (ii / 7) + 6) * 13 + ((j % 7) - (ii % 7) + 6);
            v = pos[ridx * 3 + h];
        }
        biasw[i] = v;
    }
}

// Rearrange x [64,96,56,56] fp32 -> xwin bf16 [b][win][tok(64)][ch(96)], zero pad.
// Block = (b, window-row). Reads coalesced (392-float runs), writes coalesced.
__global__ __launch_bounds__(512)
void im2win(const float* __restrict__ x, unsigned short* __restrict__ xwin)
{
    __shared__ unsigned short xs[392 * 50];   // [slab tok][ch chunk] pad 50: conflict-free
    const int tid = threadIdx.x;
    const int b = blockIdx.x >> 3, wh = blockIdx.x & 7;
    const float* xb = x + (size_t)b * 96 * 3136 + wh * 7 * 56;
    unsigned short* xo = xwin + ((size_t)b * 64 + wh * 8) * 64 * 96;
    for (int c0 = 0; c0 < 96; c0 += 48) {
        if (c0) __syncthreads();
        for (int i = tid; i < 48 * 392; i += 512) {
            int c = i / 392, t = i - c * 392;          // t = r*56 + w, contiguous
            xs[t * 50 + c] = f2bf(xb[(size_t)(c0 + c) * 3136 + t]);
        }
        __syncthreads();
        for (int i = tid; i < 8 * 64 * 48; i += 512) {
            int c = i % 48;
            int wt = (i / 48) & 63;
            int win = i / (48 * 64);
            unsigned short v = 0;
            if (wt < 49) v = xs[((wt / 7) * 56 + win * 7 + (wt % 7)) * 50 + c];
            xo[(win * 64 + wt) * 96 + c0 + c] = v;     // fully coalesced
        }
    }
}

// One block per (batch, window). 512 threads = 8 waves. 6 barriers total.
__global__ __launch_bounds__(512)
void winattn(const unsigned short* __restrict__ xwin, const float* __restrict__ bout,
             const unsigned short* __restrict__ wqkvT,
             const unsigned short* __restrict__ woutT,
             const float* __restrict__ biasw, float* __restrict__ out)
{
    extern __shared__ __align__(16) unsigned char smem[];
    unsigned short* xs   = (unsigned short*)smem;            // [64][104] window (A-frags)
    unsigned short* oall = (unsigned short*)smem;            // [64][104] overlay: xs dead after QKV
    unsigned short* qall = (unsigned short*)(smem + 13312);  // [64][104]
    unsigned short* kall = (unsigned short*)(smem + 26624);  // [64][104]
    unsigned short* vt   = (unsigned short*)(smem + 39936);  // [96][72] v transposed
    unsigned short* sp3  = (unsigned short*)(smem + 53760);  // [3][64][72] scores/probs
    float*          fin  = (float*)(smem + 13312);           // [96][68] overlays q/k

    const int tid = threadIdx.x;
    const int lane = tid & 63;
    const int w  = tid >> 6;
    const int lr = lane & 15;
    const int lk = lane >> 4;

    const int blk = blockIdx.x;
    const int b = blk >> 6, win = blk & 63;
    const int row0 = (win >> 3) * 7, col0 = (win & 7) * 7;

    // ---- stage window: one contiguous 12 KB burst -> LDS [64][104]
    const unsigned short* xg = xwin + (size_t)blk * 64 * 96;
    for (int i = tid; i < 768; i += 512) {
        int tok = i / 12, seg = i % 12;
        *(uint4*)&xs[tok * 104 + seg * 8] = *(const uint4*)&xg[tok * 96 + seg * 8];
    }
    __syncthreads();

    // ---- QKV: [64x96]@[96x288]; 72 tiles, 9 per wave
    {
        const int mi = w & 3, nb = w >> 2;
        f32x4 acc[9];
#pragma unroll
        for (int i = 0; i < 9; ++i) acc[i] = (f32x4){0.f, 0.f, 0.f, 0.f};
#pragma unroll
        for (int k = 0; k < 3; ++k) {
            bf16x8 a = *(const bf16x8*)&xs[(mi * 16 + lr) * 104 + k * 32 + lk * 8];
#pragma unroll
            for (int idx = 0; idx < 9; ++idx) {
                int ni = 2 * idx + nb;
                bf16x8 bb = *(const bf16x8*)&wqkvT[(ni * 16 + lr) * 96 + k * 32 + lk * 8];
                acc[idx] = __builtin_amdgcn_mfma_f32_16x16x32_bf16(a, bb, acc[idx], 0, 0, 0);
            }
        }
#pragma unroll
        for (int idx = 0; idx < 9; ++idx) {
            int n0 = (2 * idx + nb) * 16;
            if (n0 < 96) {
#pragma unroll
                for (int e = 0; e < 4; ++e)
                    qall[(mi * 16 + lk * 4 + e) * 104 + n0 + lr] = f2bf(acc[idx][e]);
            } else if (n0 < 192) {
#pragma unroll
                for (int e = 0; e < 4; ++e)
                    kall[(mi * 16 + lk * 4 + e) * 104 + n0 - 96 + lr] = f2bf(acc[idx][e]);
            } else {
                int d = n0 - 192 + lr;
                ushort4 pk;
                pk.x = f2bf(acc[idx][0]); pk.y = f2bf(acc[idx][1]);
                pk.z = f2bf(acc[idx][2]); pk.w = f2bf(acc[idx][3]);
                *(ushort4*)&vt[d * 72 + mi * 16 + lk * 4] = pk;
            }
        }
    }
    __syncthreads();

    // ---- S for ALL heads: 48 tiles, 6 per wave
    {
#pragma unroll
        for (int t = 0; t < 6; ++t) {
            int tile = w + 8 * t;
            int h = tile >> 4, rem = tile & 15, mi = rem >> 2, ni = rem & 3;
            bf16x8 a  = *(const bf16x8*)&qall[(mi * 16 + lr) * 104 + h * 32 + lk * 8];
            bf16x8 bb = *(const bf16x8*)&kall[(ni * 16 + lr) * 104 + h * 32 + lk * 8];
            f32x4 acc = (f32x4){0.f, 0.f, 0.f, 0.f};
            acc = __builtin_amdgcn_mfma_f32_16x16x32_bf16(a, bb, acc, 0, 0, 0);
#pragma unroll
            for (int e = 0; e < 4; ++e) {
                int i = mi * 16 + lk * 4 + e, j = ni * 16 + lr;
                sp3[h * 4608 + i * 72 + j] = f2bf(acc[e] + biasw[(h << 12) + (i << 6) + j]);
            }
        }
    }
    __syncthreads();

    // ---- softmax, all heads: 8 threads per row
    {
        const int i = tid >> 3, sub = tid & 7;
#pragma unroll
        for (int h = 0; h < 3; ++h) {
            unsigned short* sr = &sp3[h * 4608 + i * 72 + sub * 8];
            float v[8];
#pragma unroll
            for (int e = 0; e < 8; ++e) v[e] = bf2f(sr[e]);
            float m = v[0];
#pragma unroll
            for (int e = 1; e < 8; ++e) m = fmaxf(m, v[e]);
            m = fmaxf(m, __shfl_xor(m, 1));
            m = fmaxf(m, __shfl_xor(m, 2));
            m = fmaxf(m, __shfl_xor(m, 4));
            float s = 0.f;
#pragma unroll
            for (int e = 0; e < 8; ++e) { v[e] = __expf(v[e] - m); s += v[e]; }
            s += __shfl_xor(s, 1);
            s += __shfl_xor(s, 2);
            s += __shfl_xor(s, 4);
            float inv = 1.f / s;
#pragma unroll
            for (int e = 0; e < 8; ++e) sr[e] = f2bf(v[e] * inv);
        }
    }
    __syncthreads();

    // ---- PV all heads: 24 tiles, 3 per wave
    {
        const int mi = w >> 1, ni = w & 1;
#pragma unroll
        for (int h = 0; h < 3; ++h) {
            f32x4 acc = (f32x4){0.f, 0.f, 0.f, 0.f};
#pragma unroll
            for (int kk = 0; kk < 2; ++kk) {
                bf16x8 a  = *(const bf16x8*)&sp3[h * 4608 + (mi * 16 + lr) * 72 + kk * 32 + lk * 8];
                bf16x8 bb = *(const bf16x8*)&vt[(h * 32 + ni * 16 + lr) * 72 + kk * 32 + lk * 8];
                acc = __builtin_amdgcn_mfma_f32_16x16x32_bf16(a, bb, acc, 0, 0, 0);
            }
#pragma unroll
            for (int e = 0; e < 4; ++e)
                oall[(mi * 16 + lk * 4 + e) * 104 + h * 32 + ni * 16 + lr] = f2bf(acc[e]);
        }
    }
    __syncthreads();

    // ---- proj: [64x96]@[96x96]+bias; 24 tiles, 3 per wave
    {
        const int mi = w & 3, nb = w >> 2;
        f32x4 acc[3];
#pragma unroll
        for (int i = 0; i < 3; ++i) acc[i] = (f32x4){0.f, 0.f, 0.f, 0.f};
#pragma unroll
        for (int k = 0; k < 3; ++k) {
            bf16x8 a = *(const bf16x8*)&oall[(mi * 16 + lr) * 104 + k * 32 + lk * 8];
#pragma unroll
            for (int idx = 0; idx < 3; ++idx) {
                int ni = 2 * idx + nb;
                bf16x8 bb = *(const bf16x8*)&woutT[(ni * 16 + lr) * 96 + k * 32 + lk * 8];
                acc[idx] = __builtin_amdgcn_mfma_f32_16x16x32_bf16(a, bb, acc[idx], 0, 0, 0);
            }
        }
#pragma unroll
        for (int idx = 0; idx < 3; ++idx) {
            int n0 = (2 * idx + nb) * 16;
            float bias = bout[n0 + lr];
            float4 f;
            f.x = acc[idx][0] + bias; f.y = acc[idx][1] + bias;
            f.z = acc[idx][2] + bias; f.w = acc[idx][3] + bias;
            *(float4*)&fin[(n0 + lr) * 68 + mi * 16 + lk * 4] = f;
        }
    }
    __syncthreads();

    // ---- final store [b, c, H, W]
    for (int i = tid; i < 49 * 96; i += 512) {
        int c = i / 49, t = i - c * 49;
        out[((size_t)b * 96 + c) * 3136 + (row0 + t / 7) * 56 + col0 + t % 7]
            = fin[c * 68 + t];
    }
}

extern "C" void kernel_launch(void* const* d_in, const int* in_sizes, int n_in,
                              void* d_out, int out_size, void* d_ws, size_t ws_size,
                              hipStream_t stream) {
    const float* x    = (const float*)d_in[0];
    const float* wqkv = (const float*)d_in[1];
    const float* pos  = (const float*)d_in[2];
    const float* wout = (const float*)d_in[3];
    const float* bout = (const float*)d_in[4];
    float* outp = (float*)d_out;

    unsigned short* xwin  = (unsigned short*)((char*)d_ws + XWIN_OFF);
    unsigned short* wqkvT = (unsigned short*)((char*)d_ws + WQKVT_OFF);
    unsigned short* woutT = (unsigned short*)((char*)d_ws + WOUTT_OFF);
    float*          biasw = (float*)((char*)d_ws + BIAS_OFF);

    hipFuncSetAttribute((const void*)winattn,
                        hipFuncAttributeMaxDynamicSharedMemorySize, 81408);

    prep<<<dim3(64), dim3(256), 0, stream>>>(wqkv, pos, wout, wqkvT, woutT, biasw);
    im2win<<<dim3(512), dim3(512), 0, stream>>>(x, xwin);
    winattn<<<dim3(4096), dim3(512), 81408, stream>>>(xwin, bout, wqkvT, woutT, biasw, outp);
}

// Round 5
// 157.317 us; speedup vs baseline: 9.6496x; 1.0097x over previous
//
#include <hip/hip_runtime.h>

typedef __bf16 bf16;
typedef __bf16 bf16x8 __attribute__((ext_vector_type(8)));
typedef __bf16 bf16x4 __attribute__((ext_vector_type(4)));
typedef float  f32x4  __attribute__((ext_vector_type(4)));

#define SCALE 0.17677669529663687f  // 32^-0.5

// ws layout (bytes)
#define XWIN_OFF  0                  // bf16 [64][64][64][96]  padded windows
#define WQKVT_OFF 50331648           // bf16 [288][96] (q cols pre-scaled)
#define WOUTT_OFF 50386944           // bf16 [96][96]  (transposed)
#define BIAS_OFF  50405376           // float [3][64][64] (pad j>=49 -> -1e30)

__global__ __launch_bounds__(256)
void prep(const float* __restrict__ wqkv, const float* __restrict__ pos,
          const float* __restrict__ wout, bf16* __restrict__ wqkvT,
          bf16* __restrict__ woutT, float* __restrict__ biasw)
{
    int tid = blockIdx.x * 256 + threadIdx.x;
    int stride = gridDim.x * 256;
    for (int i = tid; i < 288 * 96; i += stride) {
        int n = i / 96, c = i % 96;
        float v = wqkv[c * 288 + n];
        if (n < 96) v *= SCALE;
        wqkvT[i] = (bf16)v;
    }
    for (int i = tid; i < 96 * 96; i += stride) {
        int o = i / 96, c = i % 96;
        woutT[i] = (bf16)wout[c * 96 + o];
    }
    for (int i = tid; i < 3 * 64 * 64; i += stride) {
        int h = i >> 12, r = i & 4095, ii = r >> 6, j = r & 63;
        float v;
        if (j >= 49) v = -1e30f;
        else if (ii >= 49) v = 0.f;
        else {
            int ridx = ((j / 7) - (ii / 7) + 6) * 13 + ((j % 7) - (ii % 7) + 6);
            v = pos[ridx * 3 + h];
        }
        biasw[i] = v;
    }
}

// x [64,96,56,56] fp32 -> xwin bf16 [b][win][tok(64)][ch(96)], zero pad.
__global__ __launch_bounds__(512)
void im2win(const float* __restrict__ x, bf16* __restrict__ xwin)
{
    __shared__ bf16 xs[392 * 50];
    const int tid = threadIdx.x;
    const int b = blockIdx.x >> 3, wh = blockIdx.x & 7;
    const float* xb = x + (size_t)b * 96 * 3136 + wh * 7 * 56;
    bf16* xo = xwin + ((size_t)b * 64 + wh * 8) * 64 * 96;
    for (int c0 = 0; c0 < 96; c0 += 48) {
        if (c0) __syncthreads();
        for (int i = tid; i < 48 * 392; i += 512) {
            int c = i / 392, t = i - c * 392;
            xs[t * 50 + c] = (bf16)xb[(size_t)(c0 + c) * 3136 + t];
        }
        __syncthreads();
        for (int i = tid; i < 8 * 64 * 48; i += 512) {
            int c = i % 48;
            int wt = (i / 48) & 63;
            int win = i / (48 * 64);
            bf16 v = (bf16)0.f;
            if (wt < 49) v = xs[((wt / 7) * 56 + win * 7 + (wt % 7)) * 50 + c];
            xo[(win * 64 + wt) * 96 + c0 + c] = v;
        }
    }
}

// One block per (batch, window). 512 threads = 8 waves. 5 barriers.
__global__ __launch_bounds__(512)
void winattn(const bf16* __restrict__ xwin, const float* __restrict__ bout,
             const bf16* __restrict__ wqkvT, const bf16* __restrict__ woutT,
             const float* __restrict__ biasw, float* __restrict__ out)
{
    extern __shared__ __align__(16) unsigned char smem[];
    bf16* xs   = (bf16*)smem;            // [64][104]
    bf16* oall = (bf16*)smem;            // overlay (xs dead after QKV)
    bf16* qall = (bf16*)(smem + 13312);  // [64][104]
    bf16* kall = (bf16*)(smem + 26624);  // [64][104]
    bf16* vt   = (bf16*)(smem + 39936);  // [96][72]
    bf16* sp3  = (bf16*)(smem + 53760);  // [3][64][72] P
    float* fin = (float*)(smem + 13312); // [96][68] overlays q/k

    const int tid = threadIdx.x;
    const int lane = tid & 63;
    const int w  = tid >> 6;
    const int lr = lane & 15;
    const int lk = lane >> 4;

    const int blk = blockIdx.x;
    const int b = blk >> 6, win = blk & 63;
    const int row0 = (win >> 3) * 7, col0 = (win & 7) * 7;

    // ---- strip assignment for fused S+softmax: 12 strips (3h x 4mi)
    const int hA = w >> 2, miA = w & 3;   // strips 0..7
    const int hB = 2, miB = w & 3;        // strips 8..11 (waves 0..3 only)

    // ---- prefetch biases into registers (overlaps stage+QKV phases)
    float biasA[4][4], biasB[4][4], bo[3];
#pragma unroll
    for (int ni = 0; ni < 4; ++ni)
#pragma unroll
        for (int e = 0; e < 4; ++e) {
            biasA[ni][e] = biasw[hA * 4096 + (miA * 16 + lk * 4 + e) * 64 + ni * 16 + lr];
            biasB[ni][e] = biasw[hB * 4096 + (miB * 16 + lk * 4 + e) * 64 + ni * 16 + lr];
        }
#pragma unroll
    for (int idx = 0; idx < 3; ++idx)
        bo[idx] = bout[(2 * idx + (w >> 2)) * 16 + lr];

    // ---- stage window: contiguous 12 KB -> LDS [64][104]
    const bf16* xg = xwin + (size_t)blk * 64 * 96;
    for (int i = tid; i < 768; i += 512) {
        int tok = i / 12, seg = i % 12;
        *(uint4*)&xs[tok * 104 + seg * 8] = *(const uint4*)&xg[tok * 96 + seg * 8];
    }
    __syncthreads();

    // ---- QKV: [64x96]@[96x288]; 72 tiles, 9 per wave
    {
        const int mi = w & 3, nb = w >> 2;
        f32x4 acc[9];
#pragma unroll
        for (int i = 0; i < 9; ++i) acc[i] = (f32x4){0.f, 0.f, 0.f, 0.f};
#pragma unroll
        for (int k = 0; k < 3; ++k) {
            bf16x8 a = *(const bf16x8*)&xs[(mi * 16 + lr) * 104 + k * 32 + lk * 8];
#pragma unroll
            for (int idx = 0; idx < 9; ++idx) {
                int ni = 2 * idx + nb;
                bf16x8 bb = *(const bf16x8*)&wqkvT[(ni * 16 + lr) * 96 + k * 32 + lk * 8];
                acc[idx] = __builtin_amdgcn_mfma_f32_16x16x32_bf16(a, bb, acc[idx], 0, 0, 0);
            }
        }
#pragma unroll
        for (int idx = 0; idx < 9; ++idx) {
            int n0 = (2 * idx + nb) * 16;
            if (n0 < 96) {
#pragma unroll
                for (int e = 0; e < 4; ++e)
                    qall[(mi * 16 + lk * 4 + e) * 104 + n0 + lr] = (bf16)acc[idx][e];
            } else if (n0 < 192) {
#pragma unroll
                for (int e = 0; e < 4; ++e)
                    kall[(mi * 16 + lk * 4 + e) * 104 + n0 - 96 + lr] = (bf16)acc[idx][e];
            } else {
                int d = n0 - 192 + lr;
                bf16x4 pk;
                pk[0] = (bf16)acc[idx][0]; pk[1] = (bf16)acc[idx][1];
                pk[2] = (bf16)acc[idx][2]; pk[3] = (bf16)acc[idx][3];
                *(bf16x4*)&vt[d * 72 + mi * 16 + lk * 4] = pk;
            }
        }
    }
    __syncthreads();

    // ---- S + softmax fused (row-strip per wave), write P
    {
        auto do_strip = [&](int h, int mi, float (&bias)[4][4]) {
            bf16x8 a = *(const bf16x8*)&qall[(mi * 16 + lr) * 104 + h * 32 + lk * 8];
            f32x4 acc[4];
#pragma unroll
            for (int ni = 0; ni < 4; ++ni) {
                bf16x8 bb = *(const bf16x8*)&kall[(ni * 16 + lr) * 104 + h * 32 + lk * 8];
                f32x4 z = (f32x4){0.f, 0.f, 0.f, 0.f};
                acc[ni] = __builtin_amdgcn_mfma_f32_16x16x32_bf16(a, bb, z, 0, 0, 0);
            }
#pragma unroll
            for (int ni = 0; ni < 4; ++ni)
#pragma unroll
                for (int e = 0; e < 4; ++e)
                    acc[ni][e] += bias[ni][e];
#pragma unroll
            for (int e = 0; e < 4; ++e) {
                float m = fmaxf(fmaxf(acc[0][e], acc[1][e]), fmaxf(acc[2][e], acc[3][e]));
                m = fmaxf(m, __shfl_xor(m, 1));
                m = fmaxf(m, __shfl_xor(m, 2));
                m = fmaxf(m, __shfl_xor(m, 4));
                m = fmaxf(m, __shfl_xor(m, 8));
                float p0 = __expf(acc[0][e] - m), p1 = __expf(acc[1][e] - m);
                float p2 = __expf(acc[2][e] - m), p3 = __expf(acc[3][e] - m);
                float s = (p0 + p1) + (p2 + p3);
                s += __shfl_xor(s, 1);
                s += __shfl_xor(s, 2);
                s += __shfl_xor(s, 4);
                s += __shfl_xor(s, 8);
                float inv = __builtin_amdgcn_rcpf(s);
                bf16* pr = &sp3[h * 4608 + (mi * 16 + lk * 4 + e) * 72 + lr];
                pr[0]  = (bf16)(p0 * inv);
                pr[16] = (bf16)(p1 * inv);
                pr[32] = (bf16)(p2 * inv);
                pr[48] = (bf16)(p3 * inv);
            }
        };
        do_strip(hA, miA, biasA);
        if (w < 4) do_strip(hB, miB, biasB);
    }
    __syncthreads();

    // ---- PV all heads: 24 tiles, 3 per wave
    {
        const int mi = w >> 1, ni = w & 1;
#pragma unroll
        for (int h = 0; h < 3; ++h) {
            f32x4 acc = (f32x4){0.f, 0.f, 0.f, 0.f};
#pragma unroll
            for (int kk = 0; kk < 2; ++kk) {
                bf16x8 a  = *(const bf16x8*)&sp3[h * 4608 + (mi * 16 + lr) * 72 + kk * 32 + lk * 8];
                bf16x8 bb = *(const bf16x8*)&vt[(h * 32 + ni * 16 + lr) * 72 + kk * 32 + lk * 8];
                acc = __builtin_amdgcn_mfma_f32_16x16x32_bf16(a, bb, acc, 0, 0, 0);
            }
#pragma unroll
            for (int e = 0; e < 4; ++e)
                oall[(mi * 16 + lk * 4 + e) * 104 + h * 32 + ni * 16 + lr] = (bf16)acc[e];
        }
    }
    __syncthreads();

    // ---- proj: [64x96]@[96x96]+bias; 24 tiles, 3 per wave
    {
        const int mi = w & 3, nb = w >> 2;
        f32x4 acc[3];
#pragma unroll
        for (int i = 0; i < 3; ++i) acc[i] = (f32x4){0.f, 0.f, 0.f, 0.f};
#pragma unroll
        for (int k = 0; k < 3; ++k) {
            bf16x8 a = *(const bf16x8*)&oall[(mi * 16 + lr) * 104 + k * 32 + lk * 8];
#pragma unroll
            for (int idx = 0; idx < 3; ++idx) {
                int ni = 2 * idx + nb;
                bf16x8 bb = *(const bf16x8*)&woutT[(ni * 16 + lr) * 96 + k * 32 + lk * 8];
                acc[idx] = __builtin_amdgcn_mfma_f32_16x16x32_bf16(a, bb, acc[idx], 0, 0, 0);
            }
        }
#pragma unroll
        for (int idx = 0; idx < 3; ++idx) {
            int n0 = (2 * idx + nb) * 16;
            float4 f;
            f.x = acc[idx][0] + bo[idx]; f.y = acc[idx][1] + bo[idx];
            f.z = acc[idx][2] + bo[idx]; f.w = acc[idx][3] + bo[idx];
            *(float4*)&fin[(n0 + lr) * 68 + mi * 16 + lk * 4] = f;
        }
    }
    __syncthreads();

    // ---- final store [b, c, H, W]
    for (int i = tid; i < 49 * 96; i += 512) {
        int c = i / 49, t = i - c * 49;
        out[((size_t)b * 96 + c) * 3136 + (row0 + t / 7) * 56 + col0 + t % 7]
            = fin[c * 68 + t];
    }
}

extern "C" void kernel_launch(void* const* d_in, const int* in_sizes, int n_in,
                              void* d_out, int out_size, void* d_ws, size_t ws_size,
                              hipStream_t stream) {
    const float* x    = (const float*)d_in[0];
    const float* wqkv = (const float*)d_in[1];
    const float* pos  = (const float*)d_in[2];
    const float* wout = (const float*)d_in[3];
    const float* bout = (const float*)d_in[4];
    float* outp = (float*)d_out;

    bf16*  xwin  = (bf16*)((char*)d_ws + XWIN_OFF);
    bf16*  wqkvT = (bf16*)((char*)d_ws + WQKVT_OFF);
    bf16*  woutT = (bf16*)((char*)d_ws + WOUTT_OFF);
    float* biasw = (float*)((char*)d_ws + BIAS_OFF);

    hipFuncSetAttribute((const void*)winattn,
                        hipFuncAttributeMaxDynamicSharedMemorySize, 81408);

    prep<<<dim3(64), dim3(256), 0, stream>>>(wqkv, pos, wout, wqkvT, woutT, biasw);
    im2win<<<dim3(512), dim3(512), 0, stream>>>(x, xwin);
    winattn<<<dim3(4096), dim3(512), 81408, stream>>>(xwin, bout, wqkvT, woutT, biasw, outp);
}